// Round 1
// baseline (149.583 us; speedup 1.0000x reference)
//
#include <hip/hip_runtime.h>
#include <hip/hip_bf16.h>
#include <math.h>

#define SEQ 16384
#define D   1024

// ---------------------------------------------------------------------------
// Kernel 1: logits[r] = dot(wp_h, G_Mh[row]) for r in [0, 2*SEQ)
//   r < SEQ   -> head 0 (G_M1, wp1), row = r
//   r >= SEQ  -> head 1 (G_M2, wp2), row = r - SEQ
// One wave (64 lanes) per row; float4 loads: lane i covers cols 4i..4i+3 of
// each 256-col chunk (4 chunks per 1024-col row). wp fragments preloaded.
// ---------------------------------------------------------------------------
__global__ __launch_bounds__(256) void dot_kernel(
    const float* __restrict__ g1, const float* __restrict__ g2,
    const float* __restrict__ wp1, const float* __restrict__ wp2,
    float* __restrict__ logits) {
  const int lane   = threadIdx.x & 63;
  const int wave   = (blockIdx.x * blockDim.x + threadIdx.x) >> 6;
  const int nwaves = (gridDim.x * blockDim.x) >> 6;

  // Preload both weight vectors' fragments (4 float4 each = 16 floats/lane).
  float4 w1v[4], w2v[4];
  const float4* wp1v = (const float4*)wp1;
  const float4* wp2v = (const float4*)wp2;
#pragma unroll
  for (int j = 0; j < 4; ++j) {
    w1v[j] = wp1v[lane + 64 * j];
    w2v[j] = wp2v[lane + 64 * j];
  }

  for (int r = wave; r < 2 * SEQ; r += nwaves) {
    const bool head0 = (r < SEQ);
    const float* rowp = head0 ? (g1 + (size_t)r * D)
                              : (g2 + (size_t)(r - SEQ) * D);
    const float4* rowv = (const float4*)rowp;
    float acc = 0.0f;
#pragma unroll
    for (int j = 0; j < 4; ++j) {
      float4 a = rowv[lane + 64 * j];
      float4 w = head0 ? w1v[j] : w2v[j];
      acc = fmaf(a.x, w.x, acc);
      acc = fmaf(a.y, w.y, acc);
      acc = fmaf(a.z, w.z, acc);
      acc = fmaf(a.w, w.w, acc);
    }
    // 64-lane butterfly reduction
#pragma unroll
    for (int off = 32; off > 0; off >>= 1)
      acc += __shfl_xor(acc, off, 64);
    if (lane == 0) logits[r] = acc;
  }
}

// ---------------------------------------------------------------------------
// Kernel 2: per-head softmax over SEQ logits. One block per head,
// 1024 threads, 16 elements/thread held in registers.
// ---------------------------------------------------------------------------
__global__ __launch_bounds__(1024) void softmax_kernel(
    const float* __restrict__ logits, float* __restrict__ out) {
  const int head = blockIdx.x;
  const float* x = logits + head * SEQ;
  float* y = out + head * SEQ;
  const int tid  = threadIdx.x;
  const int lane = tid & 63;
  const int wid  = tid >> 6;  // 16 waves

  float vals[16];
  float m = -INFINITY;
#pragma unroll
  for (int i = 0; i < 16; ++i) {
    float v = x[tid + i * 1024];
    vals[i] = v;
    m = fmaxf(m, v);
  }

  __shared__ float sm[16];
  __shared__ float ss[16];

  // block max
#pragma unroll
  for (int off = 32; off > 0; off >>= 1)
    m = fmaxf(m, __shfl_xor(m, off, 64));
  if (lane == 0) sm[wid] = m;
  __syncthreads();
  float bm = sm[0];
#pragma unroll
  for (int i = 1; i < 16; ++i) bm = fmaxf(bm, sm[i]);

  // exp + block sum
  float s = 0.0f;
#pragma unroll
  for (int i = 0; i < 16; ++i) {
    vals[i] = __expf(vals[i] - bm);
    s += vals[i];
  }
#pragma unroll
  for (int off = 32; off > 0; off >>= 1)
    s += __shfl_xor(s, off, 64);
  if (lane == 0) ss[wid] = s;
  __syncthreads();
  float bs = 0.0f;
#pragma unroll
  for (int i = 0; i < 16; ++i) bs += ss[i];
  const float inv = 1.0f / bs;

#pragma unroll
  for (int i = 0; i < 16; ++i)
    y[tid + i * 1024] = vals[i] * inv;
}

extern "C" void kernel_launch(void* const* d_in, const int* in_sizes, int n_in,
                              void* d_out, int out_size, void* d_ws, size_t ws_size,
                              hipStream_t stream) {
  const float* g1  = (const float*)d_in[0];  // [SEQ, D]
  const float* g2  = (const float*)d_in[1];  // [SEQ, D]
  const float* wp1 = (const float*)d_in[2];  // [1, D]
  const float* wp2 = (const float*)d_in[3];  // [1, D]
  float* out    = (float*)d_out;             // [2*SEQ] (p1_pred ++ p2_pred)
  float* logits = (float*)d_ws;              // 2*SEQ floats scratch

  // 2048 blocks x 256 thr = 8192 waves; 32768 rows -> 4 rows/wave.
  dot_kernel<<<2048, 256, 0, stream>>>(g1, g2, wp1, wp2, logits);
  softmax_kernel<<<2, 1024, 0, stream>>>(logits, out);
}